// Round 1
// baseline (1337.042 us; speedup 1.0000x reference)
//
#include <hip/hip_runtime.h>

// ---------------------------------------------------------------------------
// Fused single-head attention with the module's v-transpose bug.
// S = D = 4096. All six 4096^3 matmuls are NT GEMMs: C[m,n] = sum_k A[m,k]B[n,k].
// Round 0: m97-structure bf16 MFMA GEMM (128x128 tile, BK=64, global_load_lds).
// ---------------------------------------------------------------------------

typedef __attribute__((ext_vector_type(4))) float f32x4;
typedef __attribute__((ext_vector_type(8))) short short8;
typedef __attribute__((ext_vector_type(4))) unsigned short us4;

#define DIM 4096

__device__ __forceinline__ unsigned short f2bf(float f) {
    unsigned int u = __builtin_bit_cast(unsigned int, f);
    u += 0x7fffu + ((u >> 16) & 1u);   // round-to-nearest-even
    return (unsigned short)(u >> 16);
}

__device__ __forceinline__ void gll16(const void* g, void* l) {
    __builtin_amdgcn_global_load_lds(
        (const __attribute__((address_space(1))) unsigned int*)g,
        (__attribute__((address_space(3))) unsigned int*)l,
        16, 0, 0);
}

// ---------------------------------------------------------------------------
// fp32 -> bf16 cast, 4 elems/thread, float4 loads. grid*block*4 == n exactly.
// ---------------------------------------------------------------------------
__global__ void cast_kernel(const float* __restrict__ in, unsigned short* __restrict__ out) {
    const size_t i = ((size_t)blockIdx.x * 256 + threadIdx.x) * 4;
    float4 x = *(const float4*)(in + i);
    us4 y;
    y.x = f2bf(x.x); y.y = f2bf(x.y); y.z = f2bf(x.z); y.w = f2bf(x.w);
    *(us4*)(out + i) = y;
}

// ---------------------------------------------------------------------------
// NT GEMM: C[m,n] = sum_k A[m,k] * B[n,k], M=N=K=4096, A/B bf16 (as ushort).
// 128x128 block tile, BK=64, 256 threads = 4 waves (2x2), each wave 64x64
// via 4x4 fragments of mfma_f32_16x16x32_bf16.
// EPI: 0 = bf16 out (+optional bias), 1 = f32 out * 1/64, 2 = f32 out + bias + residual
// ---------------------------------------------------------------------------
template <int EPI>
__global__ __launch_bounds__(256)
void gemm_nt(const unsigned short* __restrict__ A, const unsigned short* __restrict__ B,
             void* __restrict__ Cout, const float* __restrict__ bias,
             const float* __restrict__ res) {
    __shared__ unsigned short Ash[128 * 64];
    __shared__ unsigned short Bsh[128 * 64];

    const int t = threadIdx.x;
    const int w = t >> 6;          // wave 0..3
    const int l = t & 63;          // lane
    const int wr = w >> 1;         // wave row (0..1)
    const int wc = w & 1;          // wave col (0..1)
    const int row0 = blockIdx.y * 128;
    const int col0 = blockIdx.x * 128;

    // staging: lane covers row (chunk*8 + l/8), k-bytes (l%8)*16 of the tile
    const int srow = l >> 3;
    const int scol = (l & 7) * 8;  // element offset in k

    f32x4 acc[4][4];
    const f32x4 zero = {0.f, 0.f, 0.f, 0.f};
#pragma unroll
    for (int m = 0; m < 4; ++m)
#pragma unroll
        for (int n = 0; n < 4; ++n) acc[m][n] = zero;

    for (int kt = 0; kt < DIM; kt += 64) {
        __syncthreads();   // previous tile fully consumed before overwrite
#pragma unroll
        for (int i = 0; i < 4; ++i) {
            const int c = i * 4 + w;       // 16 chunks of 1024B each
            gll16(A + (size_t)(row0 + c * 8 + srow) * DIM + kt + scol,
                  (char*)Ash + c * 1024);
            gll16(B + (size_t)(col0 + c * 8 + srow) * DIM + kt + scol,
                  (char*)Bsh + c * 1024);
        }
        __syncthreads();   // compiler drains vmcnt before s_barrier

#pragma unroll
        for (int kk = 0; kk < 2; ++kk) {
            short8 af[4], bfr[4];
#pragma unroll
            for (int m = 0; m < 4; ++m) {
                const int off = (wr * 64 + m * 16 + (l & 15)) * 64 + kk * 32 + (l >> 4) * 8;
                af[m] = *(const short8*)(Ash + off);
            }
#pragma unroll
            for (int n = 0; n < 4; ++n) {
                const int off = (wc * 64 + n * 16 + (l & 15)) * 64 + kk * 32 + (l >> 4) * 8;
                bfr[n] = *(const short8*)(Bsh + off);
            }
#pragma unroll
            for (int m = 0; m < 4; ++m)
#pragma unroll
                for (int n = 0; n < 4; ++n)
                    acc[m][n] = __builtin_amdgcn_mfma_f32_16x16x32_bf16(
                        af[m], bfr[n], acc[m][n], 0, 0, 0);
        }
    }

    // epilogue: C/D layout col = lane&15, row = (lane>>4)*4 + r  [m89/m91]
#pragma unroll
    for (int m = 0; m < 4; ++m) {
        const int crow0 = row0 + wr * 64 + m * 16 + ((l >> 4) << 2);
#pragma unroll
        for (int n = 0; n < 4; ++n) {
            const int ccol = col0 + wc * 64 + n * 16 + (l & 15);
            float bias_v = 0.f;
            if constexpr (EPI != 1) {
                if (bias) bias_v = bias[ccol];
            }
#pragma unroll
            for (int r = 0; r < 4; ++r) {
                const size_t idx = (size_t)(crow0 + r) * DIM + ccol;
                const float x = acc[m][n][r] + bias_v;
                if constexpr (EPI == 0) {
                    ((unsigned short*)Cout)[idx] = f2bf(x);
                } else if constexpr (EPI == 1) {
                    ((float*)Cout)[idx] = x * 0.015625f;   // 1/64
                } else {
                    ((float*)Cout)[idx] = x + res[idx];
                }
            }
        }
    }
}

// ---------------------------------------------------------------------------
// Row softmax: scores fp32 [4096][4096] -> P bf16. One block (256 thr) per row.
// ---------------------------------------------------------------------------
__global__ __launch_bounds__(256)
void softmax_kernel(const float* __restrict__ S, unsigned short* __restrict__ P) {
    const int row = blockIdx.x;
    const int t = threadIdx.x;
    const float* src = S + (size_t)row * DIM;

    float v[16];
#pragma unroll
    for (int i = 0; i < 16; ++i) v[i] = src[t + (i << 8)];

    float m = v[0];
#pragma unroll
    for (int i = 1; i < 16; ++i) m = fmaxf(m, v[i]);
#pragma unroll
    for (int off = 32; off > 0; off >>= 1) m = fmaxf(m, __shfl_xor(m, off));

    __shared__ float redm[4], reds[4];
    if ((t & 63) == 0) redm[t >> 6] = m;
    __syncthreads();
    m = fmaxf(fmaxf(redm[0], redm[1]), fmaxf(redm[2], redm[3]));

    float s = 0.f;
#pragma unroll
    for (int i = 0; i < 16; ++i) {
        v[i] = expf(v[i] - m);
        s += v[i];
    }
#pragma unroll
    for (int off = 32; off > 0; off >>= 1) s += __shfl_xor(s, off);
    if ((t & 63) == 0) reds[t >> 6] = s;
    __syncthreads();
    s = (reds[0] + reds[1]) + (reds[2] + reds[3]);

    const float inv = 1.0f / s;
    unsigned short* dst = P + (size_t)row * DIM;
#pragma unroll
    for (int i = 0; i < 16; ++i) dst[t + (i << 8)] = f2bf(v[i] * inv);
}

// ---------------------------------------------------------------------------
extern "C" void kernel_launch(void* const* d_in, const int* in_sizes, int n_in,
                              void* d_out, int out_size, void* d_ws, size_t ws_size,
                              hipStream_t stream) {
    const float* query = (const float*)d_in[0];
    const float* key   = (const float*)d_in[1];
    const float* value = (const float*)d_in[2];
    const float* Wq    = (const float*)d_in[3];
    const float* bq    = (const float*)d_in[4];
    const float* Wk    = (const float*)d_in[5];
    const float* bk    = (const float*)d_in[6];
    const float* Wv    = (const float*)d_in[7];
    const float* bv    = (const float*)d_in[8];
    const float* Wo    = (const float*)d_in[9];
    const float* bo    = (const float*)d_in[10];

    const size_t SZ = (size_t)DIM * DIM;     // 16.78M elements
    unsigned short* qb   = (unsigned short*)d_ws;
    unsigned short* kb   = qb + SZ;
    unsigned short* vb   = kb + SZ;
    unsigned short* xb   = vb + SZ;          // reused cast buffer (inputs)
    unsigned short* wb   = xb + SZ;          // reused cast buffer (weights)
    unsigned short* Pb   = wb + SZ;
    unsigned short* ctxb = Pb + SZ;
    float* scores = (float*)(ctxb + SZ);     // 4*SZ bytes
    // total ws use: 7*SZ*2 + SZ*4 = 302 MB

    const dim3 cg(16384), cb(256);           // 16384*256*4 == SZ
    const dim3 gg(32, 32), gb(256);

    // q = query @ Wq.T + bq
    cast_kernel<<<cg, cb, 0, stream>>>(query, xb);
    cast_kernel<<<cg, cb, 0, stream>>>(Wq, wb);
    gemm_nt<0><<<gg, gb, 0, stream>>>(xb, wb, qb, bq, nullptr);
    // k = key @ Wk.T + bk
    cast_kernel<<<cg, cb, 0, stream>>>(key, xb);
    cast_kernel<<<cg, cb, 0, stream>>>(Wk, wb);
    gemm_nt<0><<<gg, gb, 0, stream>>>(xb, wb, kb, bk, nullptr);
    // v = value @ Wv.T + bv
    cast_kernel<<<cg, cb, 0, stream>>>(value, xb);
    cast_kernel<<<cg, cb, 0, stream>>>(Wv, wb);
    gemm_nt<0><<<gg, gb, 0, stream>>>(xb, wb, vb, bv, nullptr);
    // scores = q @ k.T / 64   (fp32)
    gemm_nt<1><<<gg, gb, 0, stream>>>(qb, kb, scores, nullptr, nullptr);
    // P = softmax(scores)  (bf16)
    softmax_kernel<<<4096, 256, 0, stream>>>(scores, Pb);
    // ctx = P @ v.T  (the v-transpose bug makes this NT too)
    gemm_nt<0><<<gg, gb, 0, stream>>>(Pb, vb, ctxb, nullptr, nullptr);
    // out = ctx @ Wo.T + bo + value   (fp32)
    cast_kernel<<<cg, cb, 0, stream>>>(Wo, wb);
    gemm_nt<2><<<gg, gb, 0, stream>>>(ctxb, wb, d_out, bo, value);
}

// Round 2
// 842.314 us; speedup vs baseline: 1.5873x; 1.5873x over previous
//
#include <hip/hip_runtime.h>

// ---------------------------------------------------------------------------
// S = D = 4096 single-head attention (with the module's v-transpose bug).
// All six 4096^3 matmuls are NT GEMMs: C[m,n] = sum_k A[m,k]B[n,k].
// Round 2: 256x256 8-phase schedule (T1+T2+T3+T4+T5), BK=64, 8 waves,
// 128 KiB LDS dbuf, subtiled [16][32] layout + st_16x32 swizzle via
// pre-swizzled global source, counted vmcnt(2) at K-tile boundaries.
// ---------------------------------------------------------------------------

typedef __attribute__((ext_vector_type(4))) float f32x4;
typedef __attribute__((ext_vector_type(8))) short short8;
typedef __attribute__((ext_vector_type(4))) unsigned short us4;

#define DIM 4096
#define NT  64   // K tiles of 64

__device__ __forceinline__ unsigned short f2bf(float f) {
    unsigned int u = __builtin_bit_cast(unsigned int, f);
    u += 0x7fffu + ((u >> 16) & 1u);   // round-to-nearest-even
    return (unsigned short)(u >> 16);
}

__device__ __forceinline__ void gll16(const void* g, void* l) {
    __builtin_amdgcn_global_load_lds(
        (const __attribute__((address_space(1))) unsigned int*)g,
        (__attribute__((address_space(3))) unsigned int*)l,
        16, 0, 0);
}

// ---------------------------------------------------------------------------
// fp32 -> bf16 cast, 4 elems/thread. grid*block*4 == n exactly.
// ---------------------------------------------------------------------------
__global__ void cast_kernel(const float* __restrict__ in, unsigned short* __restrict__ out) {
    const size_t i = ((size_t)blockIdx.x * 256 + threadIdx.x) * 4;
    float4 x = *(const float4*)(in + i);
    us4 y;
    y.x = f2bf(x.x); y.y = f2bf(x.y); y.z = f2bf(x.z); y.w = f2bf(x.w);
    *(us4*)(out + i) = y;
}

// ---------------------------------------------------------------------------
// 256x256 8-phase NT GEMM.
// LDS element (r,k) of a [256][64] tile lives at subtile (r>>4)*2+(k>>5),
// byte (r&15)*64 + ((k&31)*2 ^ ((r&8)?32:0))  [st_16x32 swizzle].
// Staged with linear-dest global_load_lds + inverse-swizzled global source.
// EPI: 0 = bf16 out (+opt bias), 1 = f32 out * 1/64, 2 = f32 out + bias + res
// ---------------------------------------------------------------------------
template <int EPI>
__global__ __launch_bounds__(512, 2)
void gemm256(const unsigned short* __restrict__ A, const unsigned short* __restrict__ B,
             void* __restrict__ Cout, const float* __restrict__ bias,
             const float* __restrict__ res) {
    __shared__ alignas(16) char lds[131072];

    const int tid = threadIdx.x;
    const int w = tid >> 6, l = tid & 63;
    const int wr = w >> 2, wc = w & 3;          // 2 x 4 waves, wave tile 128x64

    // bijective XCD swizzle (256 blocks, 8 XCDs)
    const int bid = blockIdx.x;
    const int swz = (bid & 7) * 32 + (bid >> 3);
    const int row0 = (swz >> 4) << 8;
    const int col0 = (swz & 15) << 8;

    // lane constants
    const int laneA  = (l & 15) * 64 + ((((l >> 4) << 4)) ^ ((l & 8) << 2)); // swizzled frag-read byte
    const int sl_row = l >> 2;                                   // staging row within subtile
    const int sl_col = ((l & 3) << 3) ^ ((l & 32) ? 16 : 0);     // staging col element (inverse swz)

    f32x4 acc[8][4];
    const f32x4 zero = {0.f, 0.f, 0.f, 0.f};
#pragma unroll
    for (int m = 0; m < 8; ++m)
#pragma unroll
        for (int n = 0; n < 4; ++n) acc[m][n] = zero;

    char* const ldsp = (char*)lds;

    // stage one half-tile (128 rows x 64 k) of matrix M, tile t, half h.
    // 2 x gll16 per thread; wave w covers subtiles w and 8+w of the 16.
    auto stage = [&](const unsigned short* __restrict__ M, char* ldsMat, int rowbase,
                     int t, int h) {
        {
            const int rg = h * 8 + (w >> 1), cg = w & 1;
            gll16(M + (size_t)(rowbase + rg * 16 + sl_row) * DIM + t * 64 + cg * 32 + sl_col,
                  ldsMat + ((rg * 2 + cg) << 10));
        }
        {
            const int s = 8 + w;
            const int rg = h * 8 + (s >> 1), cg = s & 1;
            gll16(M + (size_t)(rowbase + rg * 16 + sl_row) * DIM + t * 64 + cg * 32 + sl_col,
                  ldsMat + ((rg * 2 + cg) << 10));
        }
    };

    // ---- prologue: tile0 (4 half-tiles) + A(1)h0; allow A(1)h0 in flight ----
    stage(A, ldsp,          row0, 0, 0);
    stage(A, ldsp,          row0, 0, 1);
    stage(B, ldsp + 32768,  col0, 0, 0);
    stage(B, ldsp + 32768,  col0, 0, 1);
    stage(A, ldsp + 65536,  row0, 1, 0);
    asm volatile("s_waitcnt vmcnt(2)\ns_barrier" ::: "memory");

#pragma unroll 1
    for (int t = 0; t < NT; ++t) {
        const char* Ab = ldsp + (t & 1) * 65536;
        const char* Bb = Ab + 32768;
        const int t1 = (t + 1 < NT) ? t + 1 : NT - 1;   // clamped: tail re-stages same bytes
        const int t2 = (t + 2 < NT) ? t + 2 : NT - 1;
        char* A1 = ldsp + (t1 & 1) * 65536;
        char* B1 = A1 + 32768;
        char* A2 = ldsp + (t2 & 1) * 65536;

        const int aoff = wr * 16384 + laneA;
        const int boff = wc * 8192 + laneA;

        short8 a[4][2], b0[2][2], b1[2][2];

        // ================= phase 0 : quadrant (0,0) =================
#pragma unroll
        for (int m2 = 0; m2 < 4; ++m2)
#pragma unroll
            for (int ks = 0; ks < 2; ++ks)
                a[m2][ks] = *(const short8*)(Ab + aoff + ((m2 * 2 + ks) << 10));
#pragma unroll
        for (int n2 = 0; n2 < 2; ++n2)
#pragma unroll
            for (int ks = 0; ks < 2; ++ks)
                b0[n2][ks] = *(const short8*)(Bb + boff + ((n2 * 2 + ks) << 10));
        stage(A, A1, row0, t1, 1);
        __builtin_amdgcn_s_barrier();
        asm volatile("s_waitcnt lgkmcnt(0)");
        __builtin_amdgcn_s_setprio(1);
#pragma unroll
        for (int m2 = 0; m2 < 4; ++m2)
#pragma unroll
            for (int n2 = 0; n2 < 2; ++n2)
#pragma unroll
                for (int ks = 0; ks < 2; ++ks)
                    acc[m2][n2] = __builtin_amdgcn_mfma_f32_16x16x32_bf16(
                        a[m2][ks], b0[n2][ks], acc[m2][n2], 0, 0, 0);
        __builtin_amdgcn_s_setprio(0);
        __builtin_amdgcn_s_barrier();

        // ================= phase 1 : quadrant (0,1) =================
#pragma unroll
        for (int n2 = 0; n2 < 2; ++n2)
#pragma unroll
            for (int ks = 0; ks < 2; ++ks)
                b1[n2][ks] = *(const short8*)(Bb + boff + (((2 + n2) * 2 + ks) << 10));
        stage(B, B1, col0, t1, 0);
        __builtin_amdgcn_s_barrier();
        asm volatile("s_waitcnt lgkmcnt(0)");
        __builtin_amdgcn_s_setprio(1);
#pragma unroll
        for (int m2 = 0; m2 < 4; ++m2)
#pragma unroll
            for (int n2 = 0; n2 < 2; ++n2)
#pragma unroll
                for (int ks = 0; ks < 2; ++ks)
                    acc[m2][2 + n2] = __builtin_amdgcn_mfma_f32_16x16x32_bf16(
                        a[m2][ks], b1[n2][ks], acc[m2][2 + n2], 0, 0, 0);
        __builtin_amdgcn_s_setprio(0);
        __builtin_amdgcn_s_barrier();

        // ================= phase 2 : quadrant (1,1) =================
#pragma unroll
        for (int m2 = 0; m2 < 4; ++m2)
#pragma unroll
            for (int ks = 0; ks < 2; ++ks)
                a[m2][ks] = *(const short8*)(Ab + aoff + (((4 + m2) * 2 + ks) << 10));
        stage(B, B1, col0, t1, 1);
        __builtin_amdgcn_s_barrier();
        asm volatile("s_waitcnt lgkmcnt(0)");
        __builtin_amdgcn_s_setprio(1);
#pragma unroll
        for (int m2 = 0; m2 < 4; ++m2)
#pragma unroll
            for (int n2 = 0; n2 < 2; ++n2)
#pragma unroll
                for (int ks = 0; ks < 2; ++ks)
                    acc[4 + m2][2 + n2] = __builtin_amdgcn_mfma_f32_16x16x32_bf16(
                        a[m2][ks], b1[n2][ks], acc[4 + m2][2 + n2], 0, 0, 0);
        __builtin_amdgcn_s_setprio(0);
        __builtin_amdgcn_s_barrier();

        // ================= phase 3 : quadrant (1,0) =================
        stage(A, A2, row0, t2, 0);
        __builtin_amdgcn_s_barrier();
        __builtin_amdgcn_s_setprio(1);
#pragma unroll
        for (int m2 = 0; m2 < 4; ++m2)
#pragma unroll
            for (int n2 = 0; n2 < 2; ++n2)
#pragma unroll
                for (int ks = 0; ks < 2; ++ks)
                    acc[4 + m2][n2] = __builtin_amdgcn_mfma_f32_16x16x32_bf16(
                        a[m2][ks], b0[n2][ks], acc[4 + m2][n2], 0, 0, 0);
        __builtin_amdgcn_s_setprio(0);
        // tile boundary: tile t+1 must be fully landed in every wave before
        // anyone reads it; 2 loads (A(t+2)h0) stay in flight. Fused so no
        // load/gll16 crosses it.
        asm volatile("s_waitcnt vmcnt(2)\ns_barrier" ::: "memory");
    }
    asm volatile("s_waitcnt vmcnt(0)" ::: "memory");

    // ---- epilogue: D col = lane&15, row = (lane>>4)*4 + r ----
#pragma unroll
    for (int mf = 0; mf < 8; ++mf) {
        const int grow0 = row0 + wr * 128 + mf * 16 + ((l >> 4) << 2);
#pragma unroll
        for (int nf = 0; nf < 4; ++nf) {
            const int gcol = col0 + wc * 64 + nf * 16 + (l & 15);
            float bias_v = 0.f;
            if constexpr (EPI != 1) {
                if (bias) bias_v = bias[gcol];
            }
#pragma unroll
            for (int r = 0; r < 4; ++r) {
                const size_t idx = (size_t)(grow0 + r) * DIM + gcol;
                const float x = acc[mf][nf][r] + bias_v;
                if constexpr (EPI == 0) {
                    ((unsigned short*)Cout)[idx] = f2bf(x);
                } else if constexpr (EPI == 1) {
                    ((float*)Cout)[idx] = x * 0.015625f;   // 1/64
                } else {
                    ((float*)Cout)[idx] = x + res[idx];
                }
            }
        }
    }
}

// ---------------------------------------------------------------------------
// Row softmax: scores fp32 [4096][4096] -> P bf16. One block (256 thr) per row.
// ---------------------------------------------------------------------------
__global__ __launch_bounds__(256)
void softmax_kernel(const float* __restrict__ S, unsigned short* __restrict__ P) {
    const int row = blockIdx.x;
    const int t = threadIdx.x;
    const float* src = S + (size_t)row * DIM;

    float v[16];
#pragma unroll
    for (int i = 0; i < 16; ++i) v[i] = src[t + (i << 8)];

    float m = v[0];
#pragma unroll
    for (int i = 1; i < 16; ++i) m = fmaxf(m, v[i]);
#pragma unroll
    for (int off = 32; off > 0; off >>= 1) m = fmaxf(m, __shfl_xor(m, off));

    __shared__ float redm[4], reds[4];
    if ((t & 63) == 0) redm[t >> 6] = m;
    __syncthreads();
    m = fmaxf(fmaxf(redm[0], redm[1]), fmaxf(redm[2], redm[3]));

    float s = 0.f;
#pragma unroll
    for (int i = 0; i < 16; ++i) {
        v[i] = expf(v[i] - m);
        s += v[i];
    }
#pragma unroll
    for (int off = 32; off > 0; off >>= 1) s += __shfl_xor(s, off);
    if ((t & 63) == 0) reds[t >> 6] = s;
    __syncthreads();
    s = (reds[0] + reds[1]) + (reds[2] + reds[3]);

    const float inv = 1.0f / s;
    unsigned short* dst = P + (size_t)row * DIM;
#pragma unroll
    for (int i = 0; i < 16; ++i) dst[t + (i << 8)] = f2bf(v[i] * inv);
}

// ---------------------------------------------------------------------------
extern "C" void kernel_launch(void* const* d_in, const int* in_sizes, int n_in,
                              void* d_out, int out_size, void* d_ws, size_t ws_size,
                              hipStream_t stream) {
    const float* query = (const float*)d_in[0];
    const float* key   = (const float*)d_in[1];
    const float* value = (const float*)d_in[2];
    const float* Wq    = (const float*)d_in[3];
    const float* bq    = (const float*)d_in[4];
    const float* Wk    = (const float*)d_in[5];
    const float* bk    = (const float*)d_in[6];
    const float* Wv    = (const float*)d_in[7];
    const float* bv    = (const float*)d_in[8];
    const float* Wo    = (const float*)d_in[9];
    const float* bo    = (const float*)d_in[10];

    const size_t SZ = (size_t)DIM * DIM;
    unsigned short* qb   = (unsigned short*)d_ws;
    unsigned short* kb   = qb + SZ;
    unsigned short* vb   = kb + SZ;
    unsigned short* xb   = vb + SZ;          // reused cast buffer (inputs)
    unsigned short* wb   = xb + SZ;          // reused cast buffer (weights)
    unsigned short* Pb   = wb + SZ;
    unsigned short* ctxb = Pb + SZ;
    float* scores = (float*)(ctxb + SZ);     // 4*SZ bytes

    const dim3 cg(16384), cb(256);
    const dim3 gg(256), gb(512);

    // q = query @ Wq.T + bq
    cast_kernel<<<cg, cb, 0, stream>>>(query, xb);
    cast_kernel<<<cg, cb, 0, stream>>>(Wq, wb);
    gemm256<0><<<gg, gb, 0, stream>>>(xb, wb, qb, bq, nullptr);
    // k = key @ Wk.T + bk
    cast_kernel<<<cg, cb, 0, stream>>>(key, xb);
    cast_kernel<<<cg, cb, 0, stream>>>(Wk, wb);
    gemm256<0><<<gg, gb, 0, stream>>>(xb, wb, kb, bk, nullptr);
    // v = value @ Wv.T + bv
    cast_kernel<<<cg, cb, 0, stream>>>(value, xb);
    cast_kernel<<<cg, cb, 0, stream>>>(Wv, wb);
    gemm256<0><<<gg, gb, 0, stream>>>(xb, wb, vb, bv, nullptr);
    // scores = q @ k.T / 64   (fp32)
    gemm256<1><<<gg, gb, 0, stream>>>(qb, kb, scores, nullptr, nullptr);
    // P = softmax(scores)  (bf16)
    softmax_kernel<<<4096, 256, 0, stream>>>(scores, Pb);
    // ctx = P @ v.T  (the v-transpose bug makes this NT too)
    gemm256<0><<<gg, gb, 0, stream>>>(Pb, vb, ctxb, nullptr, nullptr);
    // out = ctx @ Wo.T + bo + value   (fp32)
    cast_kernel<<<cg, cb, 0, stream>>>(Wo, wb);
    gemm256<2><<<gg, gb, 0, stream>>>(ctxb, wb, d_out, bo, value);
}